// Round 6
// baseline (817.498 us; speedup 1.0000x reference)
//
#include <hip/hip_runtime.h>

typedef _Float16 f16;
typedef _Float16 f16x4 __attribute__((ext_vector_type(4)));
typedef _Float16 f16x8 __attribute__((ext_vector_type(8)));
typedef float    f32x4 __attribute__((ext_vector_type(4)));
typedef unsigned int u32;

#define MFMA16(a,b,c) __builtin_amdgcn_mfma_f32_16x16x32_f16((a),(b),(c),0,0,0)

static __device__ __forceinline__ float sigm(float x){ return 1.0f/(1.0f + __expf(-x)); }

// ---------------- workspace layout (bytes) ----------------
static constexpr size_t OFF_WSE_P  = 0;                                  // 4 MB
static constexpr size_t OFF_WSD_P  = OFF_WSE_P  + (size_t)8192*256*2;    // 4 MB
static constexpr size_t OFF_WIHE_P = OFF_WSD_P  + (size_t)8192*256*2;    // 512 KB
static constexpr size_t OFF_WIHD_P = OFF_WIHE_P + (size_t)256*1024*2;
static constexpr size_t OFF_WHHE_P = OFF_WIHD_P + (size_t)256*1024*2;
static constexpr size_t OFF_WHHD_P = OFF_WHHE_P + (size_t)256*1024*2;
static constexpr size_t OFF_W3E    = OFF_WHHD_P + (size_t)256*1024*2;
static constexpr size_t OFF_W3D    = OFF_W3E   + (size_t)3*1024*4;
static constexpr size_t OFF_W2WO   = OFF_W3D   + (size_t)3*1024*4;
static constexpr size_t OFF_BIASE  = OFF_W2WO  + (size_t)256*3*4;
static constexpr size_t OFF_BIASD  = OFF_BIASE + (size_t)1024*4;
static constexpr size_t OFF_B2WO   = OFF_BIASD + (size_t)1024*4;
static constexpr size_t OFF_PREGE  = OFF_B2WO  + 256;                    // 10.5 MB
static constexpr size_t OFF_PREGD  = OFF_PREGE + (size_t)5120*1024*2;    // 52.4 MB
static constexpr size_t OFF_END    = OFF_PREGD + (size_t)25600*1024*2;

// ================= prep: pack weights (blocks 0-2559) + small folds (2560-2569)
// pack layout [kfg][ctg][lane][8]; element (k,n): k = kfg*32+(l>>4)*8+i, n = ctg*16+(l&15)
__global__ __launch_bounds__(256) void k_prep(
    const float* __restrict__ Wse, const float* __restrict__ Wsd,
    const float* __restrict__ Wih_e, const float* __restrict__ Wih_d,
    const float* __restrict__ Whh_e, const float* __restrict__ Whh_d,
    f16* pWse, f16* pWsd, f16* pWih_e, f16* pWih_d, f16* pWhh_e, f16* pWhh_d,
    const float* __restrict__ Wpe, const float* __restrict__ bpe,
    const float* __restrict__ bih_e, const float* __restrict__ bhh_e,
    const float* __restrict__ Wpd, const float* __restrict__ bpd,
    const float* __restrict__ bih_d, const float* __restrict__ bhh_d,
    const float* __restrict__ W2, const float* __restrict__ b2,
    const float* __restrict__ Wo, const float* __restrict__ bo,
    float* W3e, float* W3d, float* biasE, float* biasD, float* W2Wo, float* b2Wo)
{
  int blk = blockIdx.x;
  if (blk < 2560) {
    const float* W; f16* o; int N, base;
    if      (blk < 1024) { W=Wse;   o=pWse;   N=256;  base=0; }
    else if (blk < 2048) { W=Wsd;   o=pWsd;   N=256;  base=1024; }
    else if (blk < 2176) { W=Wih_e; o=pWih_e; N=1024; base=2048; }  // k rows 0..255 (sal part)
    else if (blk < 2304) { W=Wih_d; o=pWih_d; N=1024; base=2176; }
    else if (blk < 2432) { W=Whh_e; o=pWhh_e; N=1024; base=2304; }
    else                 { W=Whh_d; o=pWhh_d; N=1024; base=2432; }
    int tid = (blk - base)*256 + threadIdx.x;
    int l = tid & 63;
    int nct = N >> 4;
    int ctg = (tid >> 6) % nct;
    int kfg = (tid >> 6) / nct;
    int k0  = kfg*32 + ((l>>4)<<3);
    int col = ctg*16 + (l&15);
    f16x8 v;
#pragma unroll
    for (int i=0;i<8;++i) v[i] = (f16)W[(size_t)(k0+i)*N + col];
    *(f16x8*)(o + (size_t)tid*8) = v;
    return;
  }
  int bid = blk - 2560, tid = threadIdx.x;
  if (bid < 4) {
    int j = bid*256 + tid;
    float s0=0,s1=0,s2=0,sb=0;
    for (int m=0;m<256;++m) {
      float wv = Wih_e[(size_t)(256+m)*1024 + j];
      s0 += Wpe[m]*wv; s1 += Wpe[256+m]*wv; s2 += Wpe[512+m]*wv; sb += bpe[m]*wv;
    }
    W3e[j]=s0; W3e[1024+j]=s1; W3e[2048+j]=s2;
    biasE[j] = bih_e[j] + bhh_e[j] + sb;
  } else if (bid < 8) {
    int j = (bid-4)*256 + tid;
    float s0=0,s1=0,s2=0,sb=0;
    for (int m=0;m<256;++m) {
      float wv = Wih_d[(size_t)(256+m)*1024 + j];
      s0 += Wpd[m]*wv; s1 += Wpd[256+m]*wv; s2 += Wpd[512+m]*wv; sb += bpd[m]*wv;
    }
    W3d[j]=s0; W3d[1024+j]=s1; W3d[2048+j]=s2;
    biasD[j] = bih_d[j] + bhh_d[j] + sb;
  } else if (bid == 8) {
    int c = tid;
    float s0=0,s1=0,s2=0;
    for (int m=0;m<256;++m) {
      float wv = W2[(size_t)c*256+m];
      s0 += wv*Wo[m*3+0]; s1 += wv*Wo[m*3+1]; s2 += wv*Wo[m*3+2];
    }
    W2Wo[c*3+0]=s0; W2Wo[c*3+1]=s1; W2Wo[c*3+2]=s2;
  } else {
    if (tid < 192) {
      int j = tid >> 6, lane = tid & 63;
      float s = 0.f;
      for (int m=lane;m<256;m+=64) s += b2[m]*Wo[m*3+j];
#pragma unroll
      for (int msk=1;msk<64;msk<<=1) s += __shfl_xor(s, msk);
      if (lane==0) b2Wo[j] = s + bo[j];
    }
  }
}

// ======== fused GEMM: preg = (A(f32,K=8192)@Ws + bs) @ Wih + bias ==========
// t-major row permutation: tile rows r' = t*1024+b (64 consecutive b, fixed t);
// A-source row = b*T + t (row-contiguous reads -> same HBM bytes).
// Stage-1: 64x256 sal tile via MFMA (B direct from L2-resident packed Ws),
//          result + bs kept in LDS (f16, swizzled).
// Stage-2: 64x256 @ 256x1024 (Wih packed, L2), fragment-order preg store,
//          gate bias folded. sal never touches global memory.
__global__ __launch_bounds__(256) void k_gemm_fused(
    const float* __restrict__ A0, const f16* __restrict__ W0,
    const float* __restrict__ bs0, const f16* __restrict__ Wih0,
    const float* __restrict__ bias0, f16* __restrict__ P0, int nb0, int T0,
    const float* __restrict__ A1, const f16* __restrict__ W1,
    const float* __restrict__ bs1, const f16* __restrict__ Wih1,
    const float* __restrict__ bias1, f16* __restrict__ P1, int T1)
{
  __shared__ f16 aLDS[2][64*64];   // 16 KB: stage-1 A tiles, 16B-slot ^= row&7
  __shared__ f16 sLDS[64*256];     // 32 KB: sal tile, 16B-slot ^= row&7
  const int tid = threadIdx.x, l = tid & 63, w = tid >> 6;
  const int li = l & 15, hi = l >> 4;
  const int bx = blockIdx.x;
  const float *Ap, *bs, *bias; const f16 *Wp, *Wih; f16* P; int rblk, T;
  if (bx < nb0) { Ap=A0; Wp=W0; bs=bs0; Wih=Wih0; bias=bias0; P=P0; rblk=bx*64;        T=T0; }
  else          { Ap=A1; Wp=W1; bs=bs1; Wih=Wih1; bias=bias1; P=P1; rblk=(bx-nb0)*64;  T=T1; }
  const int t = rblk >> 10, b0 = rblk & 1023;

  f32x4 acc[4][4];
#pragma unroll
  for (int a=0;a<4;++a)
#pragma unroll
    for (int b=0;b<4;++b) acc[a][b] = (f32x4){0.f,0.f,0.f,0.f};

  const int srow = tid >> 2, kseg = tid & 3;   // 64 rows x 4 k-segs
  const float* Arow = Ap + ((size_t)(b0 + srow)*T + t)*8192 + kseg*16;

  float4 f0,f1,f2,f3;
#define LOADA(ti_) { const float* Aq = Arow + (ti_)*64;                       \
    f0 = *(const float4*)Aq;     f1 = *(const float4*)(Aq+4);                 \
    f2 = *(const float4*)(Aq+8); f3 = *(const float4*)(Aq+12); }

  LOADA(0);
  for (int ti = 0; ti < 128; ++ti) {
    const int buf = ti & 1;
    f16x8 w0, w1;
    w0[0]=(f16)f0.x; w0[1]=(f16)f0.y; w0[2]=(f16)f0.z; w0[3]=(f16)f0.w;
    w0[4]=(f16)f1.x; w0[5]=(f16)f1.y; w0[6]=(f16)f1.z; w0[7]=(f16)f1.w;
    w1[0]=(f16)f2.x; w1[1]=(f16)f2.y; w1[2]=(f16)f2.z; w1[3]=(f16)f2.w;
    w1[4]=(f16)f3.x; w1[5]=(f16)f3.y; w1[6]=(f16)f3.z; w1[7]=(f16)f3.w;
    __syncthreads();     // readers of this buf (iter ti-2) done
    *(f16x8*)&aLDS[buf][srow*64 + ((kseg*2    ) ^ (srow&7))*8] = w0;
    *(f16x8*)&aLDS[buf][srow*64 + ((kseg*2 + 1) ^ (srow&7))*8] = w1;
    if (ti + 1 < 128) LOADA(ti+1);    // prefetch flies under MFMA phase
    __syncthreads();
    const int kfg0 = ti*2;
#pragma unroll
    for (int kf = 0; kf < 2; ++kf) {
      f16x8 afr[4], bfr[4];
#pragma unroll
      for (int rt=0; rt<4; ++rt) {
        int row = rt*16 + li;
        afr[rt] = *(f16x8*)&aLDS[buf][row*64 + (((kf*4) + hi) ^ (row&7))*8];
      }
#pragma unroll
      for (int ct=0; ct<4; ++ct) {
        int ctg = w*4 + ct;
        bfr[ct] = *(const f16x8*)(Wp + ((size_t)((kfg0+kf)*16 + ctg)*64 + l)*8);
      }
#pragma unroll
      for (int rt=0; rt<4; ++rt)
#pragma unroll
        for (int ct=0; ct<4; ++ct)
          acc[rt][ct] = MFMA16(afr[rt], bfr[ct], acc[rt][ct]);
    }
  }
#undef LOADA
  // stage-1 epilogue: sal tile (+bs) -> LDS, swizzled row-major [64][256]
#pragma unroll
  for (int ct=0; ct<4; ++ct) {
    int col = (w*4 + ct)*16 + li;
    float bv = bs[col];
    int slot = col >> 3;
#pragma unroll
    for (int rt=0; rt<4; ++rt)
#pragma unroll
      for (int i=0;i<4;++i) {
        int row = rt*16 + hi*4 + i;
        sLDS[row*256 + ((slot ^ (row&7))<<3) + (col&7)] = (f16)(acc[rt][ct][i] + bv);
      }
  }
  __syncthreads();
  // stage-2: sal(64x256) @ Wih(256x1024), 4 col-chunks of 256
  const int bblk0 = b0 >> 4;
#pragma unroll
  for (int cg=0; cg<4; ++cg) {
    f32x4 a2[4][4];
#pragma unroll
    for (int a=0;a<4;++a)
#pragma unroll
      for (int b=0;b<4;++b) a2[a][b] = (f32x4){0.f,0.f,0.f,0.f};
#pragma unroll
    for (int kfg=0; kfg<8; ++kfg) {
      f16x8 afr[4], bfr[4];
#pragma unroll
      for (int rt=0; rt<4; ++rt) {
        int row = rt*16 + li;
        afr[rt] = *(f16x8*)&sLDS[row*256 + (((kfg*4 + hi) ^ (row&7))<<3)];
      }
#pragma unroll
      for (int ct=0; ct<4; ++ct) {
        int ctg2 = cg*16 + w*4 + ct;
        bfr[ct] = *(const f16x8*)(Wih + ((size_t)(kfg*64 + ctg2)*64 + l)*8);
      }
#pragma unroll
      for (int rt=0; rt<4; ++rt)
#pragma unroll
        for (int ct=0; ct<4; ++ct)
          a2[rt][ct] = MFMA16(afr[rt], bfr[ct], a2[rt][ct]);
    }
    // fragment-order store (identity with k_rnn's C-init loads), bias folded
#pragma unroll
    for (int ct=0; ct<4; ++ct) {
      const int ctg2 = cg*16 + w*4 + ct;
      const float bv = bias[ctg2*16 + li];
#pragma unroll
      for (int rt=0; rt<4; ++rt) {
        f16x4 o;
#pragma unroll
        for (int i=0;i<4;++i) o[i] = (f16)(a2[rt][ct][i] + bv);
        *(f16x4*)(P + ((size_t)((bblk0 + rt)*T + t)*64 + ctg2)*256 + l*4) = o;
      }
    }
  }
}

// ================= fused recurrent kernel: encoder(5) then decoder(25) ======
// 64 blocks x 16 rows, 512 threads (8 waves). wave w owns h-cols [w*32,+32):
// ctg = q*16 + w*2 + j -> gate quadruples lane-local.
// acc C-init from fragment-order preg (x@Wih + biases pre-folded), with
// one-step-ahead prefetch; single Whh weight stream per step (L2-resident).
__global__ __launch_bounds__(512) void k_rnn(
    const f16* __restrict__ pregE,   // [b_blk][5][64][64][4]
    const f16* __restrict__ pregD,   // [b_blk][25][64][64][4]
    const f16* __restrict__ Whh_e_p, const f16* __restrict__ Whh_d_p,
    const float* __restrict__ W3e, const float* __restrict__ W3d,
    const float* __restrict__ enc_pos, const float* __restrict__ dec_pos,
    const float* __restrict__ W2Wo, const float* __restrict__ b2Wo,
    float* __restrict__ out)         // (B,25,3)
{
  __shared__ f16 hLDS[16*256];       // swizzled (16B slot ^= row&7)
  __shared__ float W3s[3*1024];
  __shared__ float posS[2][16][4];
  __shared__ float dpart[8][16][3];
  const int tid = threadIdx.x, l = tid & 63, w = tid >> 6;
  const int li = l & 15, hi = l >> 4;
  const int bblk = blockIdx.x, rb = bblk*16;

  for (int i=tid;i<3072;i+=512) W3s[i]=W3e[i];
  float c_st[2][4];
#pragma unroll
  for (int j=0;j<2;++j)
#pragma unroll
    for (int i=0;i<4;++i) c_st[j][i]=0.f;

#define LOADPV(dst, base, t_)                                                 \
  _Pragma("unroll")                                                           \
  for (int q=0;q<4;++q)                                                       \
    _Pragma("unroll")                                                         \
    for (int j=0;j<2;++j)                                                     \
      dst[q][j] = *(const f16x4*)((base) + ((size_t)(t_)*64 + q*16 + w*2 + j)*256 + l*4);
#define LOADPP(dst, t_)                                                       \
  _Pragma("unroll")                                                           \
  for (int i=0;i<4;++i) {                                                     \
    int grow = rb + hi*4 + i;                                                 \
    dst[i][0]=enc_pos[(grow*5+(t_))*3+0];                                     \
    dst[i][1]=enc_pos[(grow*5+(t_))*3+1];                                     \
    dst[i][2]=enc_pos[(grow*5+(t_))*3+2];                                     \
  }

  // ---------------- encoder ----------------
  const f16* prE = pregE + (size_t)bblk*5*16384;   // 16384 f16 per (b_blk, t)
  f16x4 pvA[4][2], pvB[4][2];
  float ppA[4][3], ppB[4][3];
  LOADPV(pvA, prE, 0)
  LOADPP(ppA, 0)
  for (int t=0;t<5;++t) {
    if (t+1 < 5) { LOADPV(pvB, prE, t+1) LOADPP(ppB, t+1) }   // prefetch ahead
    f32x4 acc[4][2];
#pragma unroll
    for (int q=0;q<4;++q)
#pragma unroll
      for (int j=0;j<2;++j)
        acc[q][j] = (f32x4){(float)pvA[q][j][0],(float)pvA[q][j][1],(float)pvA[q][j][2],(float)pvA[q][j][3]};
    __syncthreads();               // A: prev-step hLDS writes (and t=0 W3s) visible
    if (t > 0) {
#pragma unroll
      for (int kf=0;kf<8;++kf) {
        f16x8 ah = *(f16x8*)&hLDS[li*256 + (((kf*4)+hi) ^ (li&7))*8];
#pragma unroll
        for (int q=0;q<4;++q)
#pragma unroll
          for (int j=0;j<2;++j) {
            int ctg = q*16 + w*2 + j;
            f16x8 bh = *(const f16x8*)(Whh_e_p + ((size_t)(kf*64+ctg)*64 + l)*8);
            acc[q][j] = MFMA16(ah, bh, acc[q][j]);
          }
      }
    }
    __syncthreads();               // B: hLDS reads done -> safe to rewrite
#pragma unroll
    for (int i=0;i<4;++i) {
      int r = hi*4 + i;
#pragma unroll
      for (int j=0;j<2;++j) {
        int hc = w*32 + j*16 + li;
        float gq[4];
#pragma unroll
        for (int q=0;q<4;++q) {
          int gc = q*256 + hc;
          gq[q] = acc[q][j][i] + ppA[i][0]*W3s[gc] + ppA[i][1]*W3s[1024+gc] + ppA[i][2]*W3s[2048+gc];
        }
        float cn = sigm(gq[1])*c_st[j][i] + sigm(gq[0])*tanhf(gq[2]);
        c_st[j][i] = cn;
        float h = sigm(gq[3])*tanhf(cn);
        hLDS[r*256 + (((hc>>3) ^ (r&7))<<3) + (hc&7)] = (f16)h;
      }
    }
    if (t+1 < 5) {
#pragma unroll
      for (int q=0;q<4;++q)
#pragma unroll
        for (int j=0;j<2;++j) pvA[q][j] = pvB[q][j];
#pragma unroll
      for (int i=0;i<4;++i){ ppA[i][0]=ppB[i][0]; ppA[i][1]=ppB[i][1]; ppA[i][2]=ppB[i][2]; }
    }
  }

  // ---------------- switch to decoder constants ----------------
  __syncthreads();                 // encoder gate-phase W3s reads done
  for (int i=tid;i<3072;i+=512) W3s[i]=W3d[i];
  float w2r[2][3];
#pragma unroll
  for (int j=0;j<2;++j) {
    int hc = w*32 + j*16 + li;
    w2r[j][0]=W2Wo[hc*3+0]; w2r[j][1]=W2Wo[hc*3+1]; w2r[j][2]=W2Wo[hc*3+2];
  }
  if (tid < 48) { int r=tid/3, k=tid-3*(tid/3); posS[0][r][k] = dec_pos[(size_t)(rb+r)*3 + k]; }
  const float b2w0 = b2Wo[0], b2w1 = b2Wo[1], b2w2 = b2Wo[2];

  // ---------------- decoder ----------------
  const f16* prD = pregD + (size_t)bblk*25*16384;  // 16384 f16 per (b_blk, t)
  LOADPV(pvA, prD, 0)
  int cur = 0;
  for (int t=0;t<25;++t) {
    if (t+1 < 25) LOADPV(pvB, prD, t+1)       // prefetch ahead
    f32x4 acc[4][2];
#pragma unroll
    for (int q=0;q<4;++q)
#pragma unroll
      for (int j=0;j<2;++j)
        acc[q][j] = (f32x4){(float)pvA[q][j][0],(float)pvA[q][j][1],(float)pvA[q][j][2],(float)pvA[q][j][3]};
    __syncthreads();               // A: prev hLDS/posS writes (and W3s swap) visible
#pragma unroll
    for (int kf=0;kf<8;++kf) {
      f16x8 ah = *(f16x8*)&hLDS[li*256 + (((kf*4)+hi) ^ (li&7))*8];
#pragma unroll
      for (int q=0;q<4;++q)
#pragma unroll
        for (int j=0;j<2;++j) {
          int ctg = q*16 + w*2 + j;
          f16x8 bh = *(const f16x8*)(Whh_d_p + ((size_t)(kf*64+ctg)*64 + l)*8);
          acc[q][j] = MFMA16(ah, bh, acc[q][j]);
        }
    }
    __syncthreads();               // B: hLDS reads done
    float dpar[4][3];
#pragma unroll
    for (int i=0;i<4;++i){ dpar[i][0]=0.f; dpar[i][1]=0.f; dpar[i][2]=0.f; }
#pragma unroll
    for (int i=0;i<4;++i) {
      int r = hi*4 + i;
      float p0 = posS[cur][r][0], p1 = posS[cur][r][1], p2 = posS[cur][r][2];
#pragma unroll
      for (int j=0;j<2;++j) {
        int hc = w*32 + j*16 + li;
        float gq[4];
#pragma unroll
        for (int q=0;q<4;++q) {
          int gc = q*256 + hc;
          gq[q] = acc[q][j][i] + p0*W3s[gc] + p1*W3s[1024+gc] + p2*W3s[2048+gc];
        }
        float cn = sigm(gq[1])*c_st[j][i] + sigm(gq[0])*tanhf(gq[2]);
        c_st[j][i] = cn;
        float h = sigm(gq[3])*tanhf(cn);
        hLDS[r*256 + (((hc>>3) ^ (r&7))<<3) + (hc&7)] = (f16)h;
        dpar[i][0] += h*w2r[j][0];
        dpar[i][1] += h*w2r[j][1];
        dpar[i][2] += h*w2r[j][2];
      }
    }
#pragma unroll
    for (int m=1;m<16;m<<=1)
#pragma unroll
      for (int i=0;i<4;++i) {
        dpar[i][0] += __shfl_xor(dpar[i][0], m);
        dpar[i][1] += __shfl_xor(dpar[i][1], m);
        dpar[i][2] += __shfl_xor(dpar[i][2], m);
      }
    if (li==0) {
#pragma unroll
      for (int i=0;i<4;++i) {
        int r = hi*4 + i;
        dpart[w][r][0]=dpar[i][0]; dpart[w][r][1]=dpar[i][1]; dpart[w][r][2]=dpar[i][2];
      }
    }
    __syncthreads();               // C: dpart visible
    if (tid < 16) {
      int r = tid;
      float d0=b2w0, d1=b2w1, d2=b2w2;
#pragma unroll
      for (int ww=0;ww<8;++ww){ d0+=dpart[ww][r][0]; d1+=dpart[ww][r][1]; d2+=dpart[ww][r][2]; }
      float p0 = posS[cur][r][0]+d0, p1 = posS[cur][r][1]+d1, p2 = posS[cur][r][2]+d2;
      float inv = 1.0f/sqrtf(p0*p0+p1*p1+p2*p2);
      p0*=inv; p1*=inv; p2*=inv;
      posS[cur^1][r][0]=p0; posS[cur^1][r][1]=p1; posS[cur^1][r][2]=p2;
      float* o = out + (size_t)(rb+r)*75 + t*3;
      o[0]=p0; o[1]=p1; o[2]=p2;
    }
    cur ^= 1;
#pragma unroll
    for (int q=0;q<4;++q)
#pragma unroll
      for (int j=0;j<2;++j) pvA[q][j] = pvB[q][j];
    // next iteration's barrier A orders posS/hLDS for readers
  }
#undef LOADPV
#undef LOADPP
}

// ================= launch =================
extern "C" void kernel_launch(void* const* d_in, const int* in_sizes, int n_in,
                              void* d_out, int out_size, void* d_ws, size_t ws_size,
                              hipStream_t stream)
{
  const float* enc_pos = (const float*)d_in[0];
  const float* enc_sal = (const float*)d_in[1];
  const float* dec_pos = (const float*)d_in[2];
  const float* dec_sal = (const float*)d_in[3];
  const float* Wpe  = (const float*)d_in[4];
  const float* bpe  = (const float*)d_in[5];
  const float* Wse  = (const float*)d_in[6];
  const float* bse  = (const float*)d_in[7];
  const float* Wih_e= (const float*)d_in[8];
  const float* Whh_e= (const float*)d_in[9];
  const float* bih_e= (const float*)d_in[10];
  const float* bhh_e= (const float*)d_in[11];
  const float* Wih_d= (const float*)d_in[12];
  const float* Whh_d= (const float*)d_in[13];
  const float* bih_d= (const float*)d_in[14];
  const float* bhh_d= (const float*)d_in[15];
  const float* Wpd  = (const float*)d_in[16];
  const float* bpd  = (const float*)d_in[17];
  const float* Wsd  = (const float*)d_in[18];
  const float* bsd  = (const float*)d_in[19];
  const float* W2   = (const float*)d_in[20];
  const float* b2   = (const float*)d_in[21];
  const float* Wo   = (const float*)d_in[22];
  const float* bo   = (const float*)d_in[23];

  char* ws = (char*)d_ws;
  f16* pWse   = (f16*)(ws + OFF_WSE_P);
  f16* pWsd   = (f16*)(ws + OFF_WSD_P);
  f16* pWih_e = (f16*)(ws + OFF_WIHE_P);
  f16* pWih_d = (f16*)(ws + OFF_WIHD_P);
  f16* pWhh_e = (f16*)(ws + OFF_WHHE_P);
  f16* pWhh_d = (f16*)(ws + OFF_WHHD_P);
  float* W3e  = (float*)(ws + OFF_W3E);
  float* W3d  = (float*)(ws + OFF_W3D);
  float* W2WoP= (float*)(ws + OFF_W2WO);
  float* biasE= (float*)(ws + OFF_BIASE);
  float* biasD= (float*)(ws + OFF_BIASD);
  float* b2WoP= (float*)(ws + OFF_B2WO);
  f16* pregE  = (f16*)(ws + OFF_PREGE);
  f16* pregD  = (f16*)(ws + OFF_PREGD);
  float* out  = (float*)d_out;

  hipLaunchKernelGGL(k_prep, dim3(2570), dim3(256), 0, stream,
                     Wse, Wsd, Wih_e, Wih_d, Whh_e, Whh_d,
                     pWse, pWsd, pWih_e, pWih_d, pWhh_e, pWhh_d,
                     Wpe, bpe, bih_e, bhh_e, Wpd, bpd, bih_d, bhh_d,
                     W2, b2, Wo, bo,
                     W3e, W3d, biasE, biasD, W2WoP, b2WoP);
  // fused sal-projection + pre-gate GEMM: enc tiles [0,80), dec [80,480)
  hipLaunchKernelGGL(k_gemm_fused, dim3(480), dim3(256), 0, stream,
                     enc_sal, pWse, bse, pWih_e, biasE, pregE, 80, 5,
                     dec_sal, pWsd, bsd, pWih_d, biasD, pregD, 25);
  // fused encoder+decoder recurrence
  hipLaunchKernelGGL(k_rnn, dim3(64), dim3(512), 0, stream,
                     pregE, pregD, pWhh_e, pWhh_d,
                     W3e, W3d, enc_pos, dec_pos,
                     W2WoP, b2WoP, out);
}